// Round 18
// baseline (123.893 us; speedup 1.0000x reference)
//
#include <hip/hip_runtime.h>
#include <math.h>

#define L_SEQ   1024
#define DMODEL  1024
#define DINNER  2048
#define NH      32
#define HD      64
#define NS      160     // augmented state dim = 32 rot-re + 32 rot-im + 96 plain
#define RR      32      // rotary dims
#define NPROJ   4480
#define OFF_Z   0
#define OFF_X   2048
#define OFF_B   4096
#define OFF_C   4224
#define OFF_DT  4352
#define OFF_A   4384
#define OFF_TR  4416
#define OFF_ANG 4448
#define NC      16
#define CL      64
#define PIF     3.14159265358979323846f

typedef __attribute__((ext_vector_type(8))) short bf16x8;
typedef __attribute__((ext_vector_type(4))) float f32x4;
typedef unsigned int u32;
typedef unsigned short u16;

__device__ __forceinline__ float softplusf(float x) {
  return (x > 20.f) ? x : log1pf(expf(x));
}
__device__ __forceinline__ u16 f2bf(float f) {
  u32 u = __float_as_uint(f);
  u32 r = (u + 0x7FFFu + ((u >> 16) & 1u)) >> 16;
  return (u16)r;
}
__device__ __forceinline__ float bf2f(u16 v) {
  return __uint_as_float(((u32)v) << 16);
}

// global->LDS direct DMA, 16B per lane (m97 staging path).
__device__ __forceinline__ void gload_lds16(const u16* g, u16* l) {
  __builtin_amdgcn_global_load_lds(
      (const __attribute__((address_space(1))) u32*)(unsigned long long)(const void*)g,
      (__attribute__((address_space(3))) u32*)(unsigned long long)(void*)l, 16, 0, 0);
}

// ---------------------------------------------------------------------------
// cvt2: f32 -> bf16 (RNE) for two buffers in one launch. 8 elems/thread.
// ---------------------------------------------------------------------------
__global__ __launch_bounds__(256) void cvt2_bf16(
    const float* __restrict__ s0, u16* __restrict__ d0, int q0,
    const float* __restrict__ s1, u16* __restrict__ d1, int q1) {
  int i = blockIdx.x * 256 + threadIdx.x;
  const float* s; u16* d; int j;
  if (i < q0) { s = s0; d = d0; j = i; }
  else { j = i - q0; if (j >= q1) return; s = s1; d = d1; }
  const float4* s4 = (const float4*)s;
  float4 a = s4[2 * j], b = s4[2 * j + 1];
  union { u16 h[8]; uint4 v; } o;
  o.h[0] = f2bf(a.x); o.h[1] = f2bf(a.y); o.h[2] = f2bf(a.z); o.h[3] = f2bf(a.w);
  o.h[4] = f2bf(b.x); o.h[5] = f2bf(b.y); o.h[6] = f2bf(b.z); o.h[7] = f2bf(b.w);
  ((uint4*)d)[j] = o.v;
}

// ---------------------------------------------------------------------------
// bf16 MFMA GEMM (r14-exact): m97 staging + XCD swizzle + both-sides XOR slot
// swizzle.
// ---------------------------------------------------------------------------
template <int BM, int BN, int NBM, int TOT>
__global__ __launch_bounds__(256) void gemm_bf16(
    const u16* __restrict__ A, const u16* __restrict__ B,
    float* __restrict__ C, int N, int K) {
  constexpr int BK = 32;
  constexpr int WM = BM / 2, WN = BN / 2;
  constexpr int MF = WM / 16, NF = WN / 16;
  constexpr int CA = BM / 64;
  constexpr int CB = BN / 64;
  __shared__ u16 lds[(BM + BN) * BK];

  const int i = blockIdx.x;
  const int j = (i & 7) * (TOT / 8) + (i >> 3);
  const int bm = (j % NBM) * BM;
  const int bn = (j / NBM) * BN;

  const int tid = threadIdx.x, w = tid >> 6, lane = tid & 63;
  const int wr = w >> 1, wc = w & 1;
  const int fr = lane & 15, sl = lane >> 4;
  const int lrow = lane >> 2;
  const int lslot = ((lane & 3) ^ ((lrow >> 1) & 3)) * 8;   // swizzled source

  const u16* gA[CA]; u16* lA[CA];
#pragma unroll
  for (int jj = 0; jj < CA; ++jj) {
    int ca = w * CA + jj;
    gA[jj] = A + (size_t)(bm + ca * 16 + lrow) * K + lslot;
    lA[jj] = lds + ca * 512;
  }
  const u16* gB[CB]; u16* lB[CB];
#pragma unroll
  for (int jj = 0; jj < CB; ++jj) {
    int cb = w * CB + jj;
    gB[jj] = B + (size_t)(bn + cb * 16 + lrow) * K + lslot;
    lB[jj] = lds + BM * 32 + cb * 512;
  }

  const int rsl = (sl ^ ((fr >> 1) & 3)) * 8;               // read unswizzle
  const u16* aptr[MF]; const u16* bptr[NF];
#pragma unroll
  for (int ii = 0; ii < MF; ++ii)
    aptr[ii] = lds + (wr * WM + ii * 16 + fr) * 32 + rsl;
#pragma unroll
  for (int jj = 0; jj < NF; ++jj)
    bptr[jj] = lds + BM * 32 + (wc * WN + jj * 16 + fr) * 32 + rsl;

  f32x4 acc[MF][NF] = {};
  const int iters = K / BK;

#pragma unroll
  for (int jj = 0; jj < CA; ++jj) gload_lds16(gA[jj], lA[jj]);
#pragma unroll
  for (int jj = 0; jj < CB; ++jj) gload_lds16(gB[jj], lB[jj]);

  for (int it = 0; it < iters; ++it) {
    __syncthreads();
    bf16x8 af[MF], bfv[NF];
#pragma unroll
    for (int ii = 0; ii < MF; ++ii) af[ii] = *(const bf16x8*)aptr[ii];
#pragma unroll
    for (int jj = 0; jj < NF; ++jj) bfv[jj] = *(const bf16x8*)bptr[jj];
    __syncthreads();
    if (it + 1 < iters) {
#pragma unroll
      for (int jj = 0; jj < CA; ++jj) gload_lds16(gA[jj] + (it + 1) * BK, lA[jj]);
#pragma unroll
      for (int jj = 0; jj < CB; ++jj) gload_lds16(gB[jj] + (it + 1) * BK, lB[jj]);
    }
#pragma unroll
    for (int ii = 0; ii < MF; ++ii)
#pragma unroll
      for (int jj = 0; jj < NF; ++jj)
        acc[ii][jj] = __builtin_amdgcn_mfma_f32_16x16x32_bf16(
            af[ii], bfv[jj], acc[ii][jj], 0, 0, 0);
  }

#pragma unroll
  for (int ii = 0; ii < MF; ++ii) {
    int rb = bm + wr * WM + ii * 16 + sl * 4;
#pragma unroll
    for (int jj = 0; jj < NF; ++jj) {
      int cb = bn + wc * WN + jj * 16 + fr;
#pragma unroll
      for (int r = 0; r < 4; ++r)
        C[(size_t)(rb + r) * N + cb] = acc[ii][jj][r];
    }
  }
}

// ---------------------------------------------------------------------------
// prep_theta_cvt: ONE launch, three independent block segments:
//  [0,1024)    : w_out f32->bf16
//  [1024,1152) : per-(l,h) scalars lna/beta/gamma (for uvgA)
//  [1152,2176) : theta scan per (h,r) — recomputes tanh/softplus from proj
//                with the IDENTICAL fp32 expressions (bit-identical to the
//                packed angP/dtA path), so it is independent of the scalar
//                blocks in this launch (no race; block-uniform branch).
// ---------------------------------------------------------------------------
__global__ __launch_bounds__(256) void prep_theta_cvt(
    const float* __restrict__ proj, const float* __restrict__ dt_bias,
    float* __restrict__ lnaA, float* __restrict__ betaA,
    float* __restrict__ gammaA, float* __restrict__ rc,
    float* __restrict__ rs,
    const float* __restrict__ wsrc, u16* __restrict__ wdst) {
  const int b = blockIdx.x;
  const int tid = threadIdx.x;
  __shared__ float ldssc[256];

  if (b < 1024) {                      // w_out: 2097152 elems = 262144 quads
    int j = b * 256 + tid;
    const float4* s4 = (const float4*)wsrc;
    float4 a = s4[2 * j], bb = s4[2 * j + 1];
    union { u16 h[8]; uint4 v; } o;
    o.h[0] = f2bf(a.x); o.h[1] = f2bf(a.y); o.h[2] = f2bf(a.z); o.h[3] = f2bf(a.w);
    o.h[4] = f2bf(bb.x); o.h[5] = f2bf(bb.y); o.h[6] = f2bf(bb.z); o.h[7] = f2bf(bb.w);
    ((uint4*)wdst)[j] = o.v;
    return;
  }
  if (b < 1152) {                      // scalars (dtA no longer needed)
    int idx = (b - 1024) * 256 + tid;  // l*32+h
    int h = idx & 31, l = idx >> 5;
    const float* prow = proj + (size_t)l * NPROJ;
    float dt = softplusf(prow[OFF_DT + h] + dt_bias[h]);
    float Apos = fmaxf(softplusf(prow[OFF_A + h]), 1e-4f);
    float tr = 1.f / (1.f + expf(-prow[OFF_TR + h]));
    float lna = -Apos * dt;
    float alpha = expf(lna);
    lnaA[idx] = lna;
    betaA[idx] = (1.f - tr) * dt * alpha;
    gammaA[idx] = tr * dt;
    return;
  }
  // theta scan: channel = b - 1152
  const int ch = b - 1152;
  const int h = ch >> 5;
  const int r = ch & 31;

  float csum[4];
  float run = 0.f;
#pragma unroll
  for (int i = 0; i < 4; ++i) {
    int l = tid * 4 + i;
    const float* prow = proj + (size_t)l * NPROJ;
    float ap = tanhf(prow[OFF_ANG + r]) * PIF;            // == old angP
    float dtv = softplusf(prow[OFF_DT + h] + dt_bias[h]); // == old dtA
    run += ap * dtv;
    csum[i] = run;
  }
  ldssc[tid] = run;
  __syncthreads();
  for (int off = 1; off < 256; off <<= 1) {
    float t = (tid >= off) ? ldssc[tid - off] : 0.f;
    __syncthreads();
    ldssc[tid] += t;
    __syncthreads();
  }
  float excl = ldssc[tid] - run;
#pragma unroll
  for (int i = 0; i < 4; ++i) {
    int l = tid * 4 + i;
    float th = excl + csum[i];
    size_t o = ((size_t)l * NH + h) * RR + r;
    rc[o] = cosf(th);
    rs[o] = sinf(th);
  }
}

// ---------------------------------------------------------------------------
// uvgA (r17-exact): per (h,c): builds U (global+LDS), V/G (LDS only), cumA;
// chunk FINALS (S) and Yintra. ph2/ph3 flattened to 640 items.
// ---------------------------------------------------------------------------
__global__ __launch_bounds__(256) void uvgA(
    const float* __restrict__ proj, const float* __restrict__ betaA,
    const float* __restrict__ gammaA, const float* __restrict__ lnaA,
    const float* __restrict__ rc, const float* __restrict__ rs,
    u16* __restrict__ U, float* __restrict__ cumA, float* __restrict__ adec,
    u16* __restrict__ S, u16* __restrict__ Yb) {
  const int h = blockIdx.x >> 4, c = blockIdx.x & 15;
  const int c0 = c * CL;
  const int tid = threadIdx.x;
  const int w = tid >> 6, lane = tid & 63;
  const int wr = w >> 1, wc = w & 1;
  const int fr = lane & 15, sl = lane >> 4;

  __shared__ __attribute__((aligned(16))) char smem[76288];
  u16 (*Gl)[72]   = (u16(*)[72])(smem);              // [64][72] raw G^T
  float* wsc      = (float*)(smem + 9216);           // [64]
  float* bet      = (float*)(smem + 9472);           // [64]
  float* gam      = (float*)(smem + 9728);           // [64]
  float* cums     = (float*)(smem + 9984);           // [64]
  float (*xs)[64] = (float(*)[64])(smem + 10240);    // [65][64]
  u16 (*Ul)[168]  = (u16(*)[168])(smem + 10240);     // aliases xs (after ph1)
  u16 (*Vl)[168]  = (u16(*)[168])(smem + 31744);     // [64][168]
  u16 (*Vt)[72]   = (u16(*)[72])(smem + 53248);      // [160][72] (scaled)
  u16 (*Ml)[72]   = (u16(*)[72])(smem + 53248);      // aliases Vt (after ph4)

  // ph0: stage xs; wave3: cumA scan + wsc/bet/gam/cums
  if (w < 3) {
    for (int i = tid; i < 65 * 16; i += 192) {
      int r = i >> 4, c4 = i & 15;
      int l = c0 - 1 + r;
      float4 v = {0.f, 0.f, 0.f, 0.f};
      if (l >= 0)
        v = *(const float4*)(proj + (size_t)l * NPROJ + OFF_X + h * HD + c4 * 4);
      *(float4*)&xs[r][c4 * 4] = v;
    }
  } else {
    const int t = lane;
    float v = lnaA[(c0 + t) * NH + h];
#pragma unroll
    for (int k = 1; k < 64; k <<= 1) {
      int src = t - k;
      float o = __shfl(v, src < 0 ? 0 : src);
      if (t >= k) v += o;
    }
    cumA[(size_t)h * L_SEQ + c0 + t] = v;
    if (t == 63) adec[h * NC + c] = expf(v);
    float c63 = __shfl(v, 63);
    cums[t] = v;
    wsc[t] = expf(c63 - v);
    bet[t] = betaA[(c0 + t) * NH + h];
    gam[t] = gammaA[(c0 + t) * NH + h];
  }
  __syncthreads();

  // ph1: G build (raw) -> Gl[p][s], lane = p
  {
    const int p = lane;
    union { u16 hh[16]; uint4 q[2]; } og;
    float xprev = xs[w * 16][p];
#pragma unroll
    for (int i = 0; i < 16; ++i) {
      int s = w * 16 + i;
      float xcur = xs[s + 1][p];
      og.hh[i] = f2bf(bet[s] * xprev + gam[s] * xcur);
      xprev = xcur;
    }
    *(uint4*)&Gl[p][w * 16] = og.q[0];
    *(uint4*)&Gl[p][w * 16 + 8] = og.q[1];
  }
  __syncthreads();       // xs dead; Ul region writable

  // ph2: U/V build — 640 items (n, quarter), n = it % 160 keeps lane
  // coalescing identical to the old layout; each item covers 16 ss steps.
  for (int it = tid; it < 640; it += 256) {
    const int n = it % 160;
    const int q = it / 160;
    const int idxB = (n < 64) ? (n & 31) : (n - 32);
    const bool is_re = (n < 32);
    const bool has_rot = (n < 64);
#pragma unroll
    for (int k = 0; k < 16; ++k) {
      int ss = q * 16 + k;
      int l = c0 + ss;
      const float* prow = proj + (size_t)l * NPROJ;
      float Bv = prow[OFF_B + idxB];
      float Cv = prow[OFF_C + idxB];
      if (has_rot) {
        float rv = is_re ? rc[((size_t)l * NH + h) * RR + idxB]
                         : rs[((size_t)l * NH + h) * RR + idxB];
        Bv *= rv; Cv *= rv;
      }
      u16 uu = f2bf(Cv);
      U[((size_t)h * L_SEQ + l) * NS + n] = uu;
      Ul[ss][n] = uu;
      Vl[ss][n] = f2bf(Bv);
    }
  }
  __syncthreads();

  // ph3: transpose+scale Vl -> Vt — 640 items (n, quarter of 8 s-pairs)
  for (int it = tid; it < 640; it += 256) {
    const int n = it % 160;
    const int q = it / 160;
#pragma unroll
    for (int k = 0; k < 8; ++k) {
      int s2 = q * 8 + k;
      float w0 = wsc[2 * s2], w1 = wsc[2 * s2 + 1];
      u32 lo = (u32)f2bf(bf2f(Vl[2 * s2][n]) * w0);
      u32 hi = (u32)f2bf(bf2f(Vl[2 * s2 + 1][n]) * w1);
      *(u32*)&Vt[n][2 * s2] = lo | (hi << 16);
    }
  }
  __syncthreads();

  // ph4: finals MFMA  F[p,n] = sum_s G[s,p] * wsc[s]*V[s,n]  (Gl x Vt)
  {
    f32x4 acc[2][5] = {};
#pragma unroll
    for (int ks = 0; ks < 2; ++ks) {
      bf16x8 a0 = *(const bf16x8*)&Gl[wr * 32 + fr][ks * 32 + sl * 8];
      bf16x8 a1 = *(const bf16x8*)&Gl[wr * 32 + 16 + fr][ks * 32 + sl * 8];
      bf16x8 bv[5];
#pragma unroll
      for (int fj = 0; fj < 5; ++fj)
        bv[fj] = *(const bf16x8*)&Vt[wc * 80 + fj * 16 + fr][ks * 32 + sl * 8];
#pragma unroll
      for (int fj = 0; fj < 5; ++fj) {
        acc[0][fj] = __builtin_amdgcn_mfma_f32_16x16x32_bf16(a0, bv[fj], acc[0][fj], 0, 0, 0);
        acc[1][fj] = __builtin_amdgcn_mfma_f32_16x16x32_bf16(a1, bv[fj], acc[1][fj], 0, 0, 0);
      }
    }
    u16* Fb = S + (size_t)(c * NH + h) * HD * NS;
#pragma unroll
    for (int fi = 0; fi < 2; ++fi)
#pragma unroll
      for (int fj = 0; fj < 5; ++fj)
#pragma unroll
        for (int r = 0; r < 4; ++r) {
          int p = wr * 32 + fi * 16 + sl * 4 + r;
          int n = wc * 80 + fj * 16 + fr;
          Fb[(size_t)p * NS + n] = f2bf(acc[fi][fj][r]);
        }
  }

  // ph5: P1 = Ul @ Vl^T (t rows, s cols), then M -> Ml (overwrites Vt)
  f32x4 pac[2][2] = {};
#pragma unroll
  for (int ks = 0; ks < 5; ++ks) {
    bf16x8 a0 = *(const bf16x8*)&Ul[wr * 32 + fr][ks * 32 + sl * 8];
    bf16x8 a1 = *(const bf16x8*)&Ul[wr * 32 + 16 + fr][ks * 32 + sl * 8];
    bf16x8 b0 = *(const bf16x8*)&Vl[wc * 32 + fr][ks * 32 + sl * 8];
    bf16x8 b1 = *(const bf16x8*)&Vl[wc * 32 + 16 + fr][ks * 32 + sl * 8];
    pac[0][0] = __builtin_amdgcn_mfma_f32_16x16x32_bf16(a0, b0, pac[0][0], 0, 0, 0);
    pac[0][1] = __builtin_amdgcn_mfma_f32_16x16x32_bf16(a0, b1, pac[0][1], 0, 0, 0);
    pac[1][0] = __builtin_amdgcn_mfma_f32_16x16x32_bf16(a1, b0, pac[1][0], 0, 0, 0);
    pac[1][1] = __builtin_amdgcn_mfma_f32_16x16x32_bf16(a1, b1, pac[1][1], 0, 0, 0);
  }
  __syncthreads();   // all waves done reading Vt (ph4) before Ml overwrite
#pragma unroll
  for (int fi = 0; fi < 2; ++fi)
#pragma unroll
    for (int fj = 0; fj < 2; ++fj)
#pragma unroll
      for (int r = 0; r < 4; ++r) {
        int t = wr * 32 + fi * 16 + sl * 4 + r;
        int ss = wc * 32 + fj * 16 + fr;
        float m = (ss <= t) ? expf(cums[t] - cums[ss]) * pac[fi][fj][r] : 0.f;
        Ml[t][ss] = f2bf(m);
      }
  __syncthreads();

  // ph6: Yintra = Ml @ Gl^T  -> Yb (bf16)
  {
    f32x4 yac[2][2] = {};
#pragma unroll
    for (int ks = 0; ks < 2; ++ks) {
      bf16x8 a0 = *(const bf16x8*)&Ml[wr * 32 + fr][ks * 32 + sl * 8];
      bf16x8 a1 = *(const bf16x8*)&Ml[wr * 32 + 16 + fr][ks * 32 + sl * 8];
      bf16x8 b0 = *(const bf16x8*)&Gl[wc * 32 + fr][ks * 32 + sl * 8];
      bf16x8 b1 = *(const bf16x8*)&Gl[wc * 32 + 16 + fr][ks * 32 + sl * 8];
      yac[0][0] = __builtin_amdgcn_mfma_f32_16x16x32_bf16(a0, b0, yac[0][0], 0, 0, 0);
      yac[0][1] = __builtin_amdgcn_mfma_f32_16x16x32_bf16(a0, b1, yac[0][1], 0, 0, 0);
      yac[1][0] = __builtin_amdgcn_mfma_f32_16x16x32_bf16(a1, b0, yac[1][0], 0, 0, 0);
      yac[1][1] = __builtin_amdgcn_mfma_f32_16x16x32_bf16(a1, b1, yac[1][1], 0, 0, 0);
    }
#pragma unroll
    for (int fi = 0; fi < 2; ++fi)
#pragma unroll
      for (int fj = 0; fj < 2; ++fj)
#pragma unroll
        for (int r = 0; r < 4; ++r) {
          int t = wr * 32 + fi * 16 + sl * 4 + r;
          int p = wc * 32 + fj * 16 + fr;
          Yb[(size_t)(c0 + t) * DINNER + h * HD + p] = f2bf(yac[fi][fj][r]);
        }
  }
}

// ---------------------------------------------------------------------------
// combine (r11-exact): sequential over 16 chunks per (h,p,n); finals->inits.
// ---------------------------------------------------------------------------
__global__ __launch_bounds__(256) void combine(
    u16* __restrict__ S, const float* __restrict__ adec) {
  const int idx = blockIdx.x * 256 + threadIdx.x;
  if (idx >= NH * HD * NS) return;
  const int n = idx % NS;
  const int rem = idx / NS;
  const int p = rem & 63;
  const int h = rem >> 6;
  float F = 0.f;
  for (int c = 0; c < NC; ++c) {
    size_t off = ((size_t)(c * NH + h) * HD + p) * NS + n;
    float sv = bf2f(S[off]);
    S[off] = f2bf(F);
    F = fmaf(F, adec[h * NC + c], sv);
  }
}

// ---------------------------------------------------------------------------
// passC (r13-exact): y = ecum[t]*(U@S0^T) + Yintra + D*x, gated. One barrier.
// ---------------------------------------------------------------------------
__global__ __launch_bounds__(256) void passC(
    const float* __restrict__ proj, const u16* __restrict__ U,
    const float* __restrict__ cumA, const u16* __restrict__ S,
    const u16* __restrict__ Yb, const float* __restrict__ Dvec,
    u16* __restrict__ yz) {
  const int c = blockIdx.x >> 5, h = blockIdx.x & 31;
  const int c0 = c * CL;
  const int tid = threadIdx.x;
  const int w = tid >> 6, lane = tid & 63;
  const int wr = w >> 1, wc = w & 1;
  const int fr = lane & 15, sl = lane >> 4;
  __shared__ u16 Ul[64][168];
  __shared__ u16 BB[64][168];
  __shared__ float ecum[64];

  const u16* Us = U + ((size_t)h * L_SEQ + c0) * NS;
  for (int i = tid; i < 1280; i += 256) {
    int r = i / 20, ch = i % 20;
    *(uint4*)&Ul[r][ch * 8] = *(const uint4*)(Us + (size_t)r * NS + ch * 8);
  }
  {
    const u16* S0 = S + (size_t)(c * NH + h) * HD * NS;
    for (int i = tid; i < 1280; i += 256) {
      int r = i / 20, ch = i % 20;
      *(uint4*)&BB[r][ch * 8] = *(const uint4*)(S0 + (size_t)r * NS + ch * 8);
    }
  }
  if (tid < 64) ecum[tid] = expf(cumA[(size_t)h * L_SEQ + c0 + tid]);
  __syncthreads();

  f32x4 acc[2][2] = {};
#pragma unroll
  for (int ks = 0; ks < 5; ++ks) {
    bf16x8 a0 = *(const bf16x8*)&Ul[wr * 32 + fr][ks * 32 + sl * 8];
    bf16x8 a1 = *(const bf16x8*)&Ul[wr * 32 + 16 + fr][ks * 32 + sl * 8];
    bf16x8 b0 = *(const bf16x8*)&BB[wc * 32 + fr][ks * 32 + sl * 8];
    bf16x8 b1 = *(const bf16x8*)&BB[wc * 32 + 16 + fr][ks * 32 + sl * 8];
    acc[0][0] = __builtin_amdgcn_mfma_f32_16x16x32_bf16(a0, b0, acc[0][0], 0, 0, 0);
    acc[0][1] = __builtin_amdgcn_mfma_f32_16x16x32_bf16(a0, b1, acc[0][1], 0, 0, 0);
    acc[1][0] = __builtin_amdgcn_mfma_f32_16x16x32_bf16(a1, b0, acc[1][0], 0, 0, 0);
    acc[1][1] = __builtin_amdgcn_mfma_f32_16x16x32_bf16(a1, b1, acc[1][1], 0, 0, 0);
  }

  const float Dh = Dvec[h];
#pragma unroll
  for (int fi = 0; fi < 2; ++fi)
#pragma unroll
    for (int fj = 0; fj < 2; ++fj)
#pragma unroll
      for (int r = 0; r < 4; ++r) {
        int t = wr * 32 + fi * 16 + sl * 4 + r;
        int p = wc * 32 + fj * 16 + fr;
        int l = c0 + t;
        float y = acc[fi][fj][r] * ecum[t] +
                  bf2f(Yb[(size_t)l * DINNER + h * HD + p]);
        float x = proj[(size_t)l * NPROJ + OFF_X + h * HD + p];
        float z = proj[(size_t)l * NPROJ + OFF_Z + h * HD + p];
        y += Dh * x;
        float sg = z / (1.f + expf(-z));
        yz[(size_t)l * DINNER + h * HD + p] = f2bf(y * sg);
      }
}

// ---------------------------------------------------------------------------
extern "C" void kernel_launch(void* const* d_in, const int* in_sizes, int n_in,
                              void* d_out, int out_size, void* d_ws, size_t ws_size,
                              hipStream_t stream) {
  const float* u       = (const float*)d_in[0];
  const float* w_in    = (const float*)d_in[1];
  const float* w_out   = (const float*)d_in[2];
  const float* dt_bias = (const float*)d_in[3];
  const float* Dvec    = (const float*)d_in[4];
  float* out = (float*)d_out;

  float* ws = (float*)d_ws;
  float* proj   = ws;                          // 4,587,520 f
  float* lnaA   = proj + 4587520;              // 32768
  float* betaA  = lnaA + 32768;
  float* gammaA = betaA + 32768;
  float* cumA   = gammaA + 32768;
  float* adec   = cumA + 32768;                // 512
  float* rcb    = adec + 512;                  // 1,048,576
  float* rsb    = rcb + 1048576;               // 1,048,576
  u16*   Sb     = (u16*)(rsb + 1048576);       // 5,242,880 u16 (chunk states)
  u16*   Ubuf   = Sb + 5242880;                // 5,242,880 u16
  u16*   Yb     = Ubuf + 5242880;              // 2,097,152 u16 (Yintra)
  u16*   yzb    = Yb + 2097152;                // 2,097,152 u16
  u16*   wob    = yzb + 2097152;               // 2,097,152 u16
  // epoch-1 overlay (dead before uvgA writes Sb/Ubuf):
  u16*   ub     = Sb;                          // 1,048,576 u16
  u16*   wib    = Sb + 1048576;                // 4,587,520 u16 (spills into Ubuf)

  // 1. u + w_in -> bf16
  cvt2_bf16<<<(131072 + 573440) / 256, 256, 0, stream>>>(
      u, ub, 131072, w_in, wib, 573440);

  // 2. proj = u @ w_in^T  (64x128, 560 blocks, XCD-swizzled)
  gemm_bf16<64, 128, 16, 560><<<560, 256, 0, stream>>>(
      ub, wib, proj, NPROJ, DMODEL);

  // 3. w_out cvt + scalars + theta (one launch, 3 independent segments)
  prep_theta_cvt<<<1024 + 128 + 1024, 256, 0, stream>>>(
      proj, dt_bias, lnaA, betaA, gammaA, rcb, rsb, w_out, wob);

  // 4. U/cumA build + chunk finals + intra-chunk Y (V/Gt stay in LDS)
  uvgA<<<NH * NC, 256, 0, stream>>>(
      proj, betaA, gammaA, lnaA, rcb, rsb, Ubuf, cumA, adec, Sb, Yb);

  // 5. cross-chunk combine
  combine<<<(NH * HD * NS + 255) / 256, 256, 0, stream>>>(Sb, adec);

  // 6. y = P2*ecum + Yintra + D*x, gate -> yz
  passC<<<NC * NH, 256, 0, stream>>>(
      proj, Ubuf, cumA, Sb, Yb, Dvec, yzb);

  // 7. out = yz @ w_out^T  (64x64, 256 blocks, XCD-swizzled)
  gemm_bf16<64, 64, 16, 256><<<256, 256, 0, stream>>>(
      yzb, wob, out, DMODEL, DINNER);
}

// Round 19
// 121.576 us; speedup vs baseline: 1.0191x; 1.0191x over previous
//
#include <hip/hip_runtime.h>
#include <math.h>

#define L_SEQ   1024
#define DMODEL  1024
#define DINNER  2048
#define NH      32
#define HD      64
#define NS      160     // augmented state dim = 32 rot-re + 32 rot-im + 96 plain
#define RR      32      // rotary dims
#define NPROJ   4480
#define OFF_Z   0
#define OFF_X   2048
#define OFF_B   4096
#define OFF_C   4224
#define OFF_DT  4352
#define OFF_A   4384
#define OFF_TR  4416
#define OFF_ANG 4448
#define NC      16
#define CL      64
#define PIF     3.14159265358979323846f

typedef __attribute__((ext_vector_type(8))) short bf16x8;
typedef __attribute__((ext_vector_type(4))) float f32x4;
typedef unsigned int u32;
typedef unsigned short u16;

__device__ __forceinline__ float softplusf(float x) {
  return (x > 20.f) ? x : log1pf(expf(x));
}
__device__ __forceinline__ u16 f2bf(float f) {
  u32 u = __float_as_uint(f);
  u32 r = (u + 0x7FFFu + ((u >> 16) & 1u)) >> 16;
  return (u16)r;
}
__device__ __forceinline__ float bf2f(u16 v) {
  return __uint_as_float(((u32)v) << 16);
}

// global->LDS direct DMA, 16B per lane (m97 staging path).
__device__ __forceinline__ void gload_lds16(const u16* g, u16* l) {
  __builtin_amdgcn_global_load_lds(
      (const __attribute__((address_space(1))) u32*)(unsigned long long)(const void*)g,
      (__attribute__((address_space(3))) u32*)(unsigned long long)(void*)l, 16, 0, 0);
}

// ---------------------------------------------------------------------------
// cvt2: f32 -> bf16 (RNE) for two buffers in one launch. 8 elems/thread.
// ---------------------------------------------------------------------------
__global__ __launch_bounds__(256) void cvt2_bf16(
    const float* __restrict__ s0, u16* __restrict__ d0, int q0,
    const float* __restrict__ s1, u16* __restrict__ d1, int q1) {
  int i = blockIdx.x * 256 + threadIdx.x;
  const float* s; u16* d; int j;
  if (i < q0) { s = s0; d = d0; j = i; }
  else { j = i - q0; if (j >= q1) return; s = s1; d = d1; }
  const float4* s4 = (const float4*)s;
  float4 a = s4[2 * j], b = s4[2 * j + 1];
  union { u16 h[8]; uint4 v; } o;
  o.h[0] = f2bf(a.x); o.h[1] = f2bf(a.y); o.h[2] = f2bf(a.z); o.h[3] = f2bf(a.w);
  o.h[4] = f2bf(b.x); o.h[5] = f2bf(b.y); o.h[6] = f2bf(b.z); o.h[7] = f2bf(b.w);
  ((uint4*)d)[j] = o.v;
}

// ---------------------------------------------------------------------------
// bf16 MFMA GEMM (r14-exact): m97 staging + XCD swizzle + both-sides XOR slot
// swizzle.
// ---------------------------------------------------------------------------
template <int BM, int BN, int NBM, int TOT>
__global__ __launch_bounds__(256) void gemm_bf16(
    const u16* __restrict__ A, const u16* __restrict__ B,
    float* __restrict__ C, int N, int K) {
  constexpr int BK = 32;
  constexpr int WM = BM / 2, WN = BN / 2;
  constexpr int MF = WM / 16, NF = WN / 16;
  constexpr int CA = BM / 64;
  constexpr int CB = BN / 64;
  __shared__ u16 lds[(BM + BN) * BK];

  const int i = blockIdx.x;
  const int j = (i & 7) * (TOT / 8) + (i >> 3);
  const int bm = (j % NBM) * BM;
  const int bn = (j / NBM) * BN;

  const int tid = threadIdx.x, w = tid >> 6, lane = tid & 63;
  const int wr = w >> 1, wc = w & 1;
  const int fr = lane & 15, sl = lane >> 4;
  const int lrow = lane >> 2;
  const int lslot = ((lane & 3) ^ ((lrow >> 1) & 3)) * 8;   // swizzled source

  const u16* gA[CA]; u16* lA[CA];
#pragma unroll
  for (int jj = 0; jj < CA; ++jj) {
    int ca = w * CA + jj;
    gA[jj] = A + (size_t)(bm + ca * 16 + lrow) * K + lslot;
    lA[jj] = lds + ca * 512;
  }
  const u16* gB[CB]; u16* lB[CB];
#pragma unroll
  for (int jj = 0; jj < CB; ++jj) {
    int cb = w * CB + jj;
    gB[jj] = B + (size_t)(bn + cb * 16 + lrow) * K + lslot;
    lB[jj] = lds + BM * 32 + cb * 512;
  }

  const int rsl = (sl ^ ((fr >> 1) & 3)) * 8;               // read unswizzle
  const u16* aptr[MF]; const u16* bptr[NF];
#pragma unroll
  for (int ii = 0; ii < MF; ++ii)
    aptr[ii] = lds + (wr * WM + ii * 16 + fr) * 32 + rsl;
#pragma unroll
  for (int jj = 0; jj < NF; ++jj)
    bptr[jj] = lds + BM * 32 + (wc * WN + jj * 16 + fr) * 32 + rsl;

  f32x4 acc[MF][NF] = {};
  const int iters = K / BK;

#pragma unroll
  for (int jj = 0; jj < CA; ++jj) gload_lds16(gA[jj], lA[jj]);
#pragma unroll
  for (int jj = 0; jj < CB; ++jj) gload_lds16(gB[jj], lB[jj]);

  for (int it = 0; it < iters; ++it) {
    __syncthreads();
    bf16x8 af[MF], bfv[NF];
#pragma unroll
    for (int ii = 0; ii < MF; ++ii) af[ii] = *(const bf16x8*)aptr[ii];
#pragma unroll
    for (int jj = 0; jj < NF; ++jj) bfv[jj] = *(const bf16x8*)bptr[jj];
    __syncthreads();
    if (it + 1 < iters) {
#pragma unroll
      for (int jj = 0; jj < CA; ++jj) gload_lds16(gA[jj] + (it + 1) * BK, lA[jj]);
#pragma unroll
      for (int jj = 0; jj < CB; ++jj) gload_lds16(gB[jj] + (it + 1) * BK, lB[jj]);
    }
#pragma unroll
    for (int ii = 0; ii < MF; ++ii)
#pragma unroll
      for (int jj = 0; jj < NF; ++jj)
        acc[ii][jj] = __builtin_amdgcn_mfma_f32_16x16x32_bf16(
            af[ii], bfv[jj], acc[ii][jj], 0, 0, 0);
  }

#pragma unroll
  for (int ii = 0; ii < MF; ++ii) {
    int rb = bm + wr * WM + ii * 16 + sl * 4;
#pragma unroll
    for (int jj = 0; jj < NF; ++jj) {
      int cb = bn + wc * WN + jj * 16 + fr;
#pragma unroll
      for (int r = 0; r < 4; ++r)
        C[(size_t)(rb + r) * N + cb] = acc[ii][jj][r];
    }
  }
}

// ---------------------------------------------------------------------------
// prep_scalars_cvt (r14-exact): blocks <1024 convert w_out; blocks >=1024 do
// per-(l,h) scalars: dt, ln(alpha), beta, gamma, angP = tanh(ang)*pi.
// ---------------------------------------------------------------------------
__global__ __launch_bounds__(256) void prep_scalars_cvt(
    const float* __restrict__ proj, const float* __restrict__ dt_bias,
    float* __restrict__ dtA, float* __restrict__ lnaA,
    float* __restrict__ betaA, float* __restrict__ gammaA,
    float* __restrict__ angP,
    const float* __restrict__ wsrc, u16* __restrict__ wdst) {
  const int b = blockIdx.x;
  if (b < 1024) {
    int j = b * 256 + threadIdx.x;
    const float4* s4 = (const float4*)wsrc;
    float4 a = s4[2 * j], bb = s4[2 * j + 1];
    union { u16 h[8]; uint4 v; } o;
    o.h[0] = f2bf(a.x); o.h[1] = f2bf(a.y); o.h[2] = f2bf(a.z); o.h[3] = f2bf(a.w);
    o.h[4] = f2bf(bb.x); o.h[5] = f2bf(bb.y); o.h[6] = f2bf(bb.z); o.h[7] = f2bf(bb.w);
    ((uint4*)wdst)[j] = o.v;
    return;
  }
  int idx = (b - 1024) * 256 + threadIdx.x;   // l*32+h
  int h = idx & 31, l = idx >> 5;
  const float* prow = proj + (size_t)l * NPROJ;
  float dt = softplusf(prow[OFF_DT + h] + dt_bias[h]);
  float Apos = fmaxf(softplusf(prow[OFF_A + h]), 1e-4f);
  float tr = 1.f / (1.f + expf(-prow[OFF_TR + h]));
  float lna = -Apos * dt;
  float alpha = expf(lna);
  dtA[idx] = dt;
  lnaA[idx] = lna;
  betaA[idx] = (1.f - tr) * dt * alpha;
  gammaA[idx] = tr * dt;
  angP[idx] = tanhf(prow[OFF_ANG + h]) * PIF;
}

// ---------------------------------------------------------------------------
// theta_scan (r11-exact): cumsum over L of angP*dt -> rc, rs. Block per (h,r).
// ---------------------------------------------------------------------------
__global__ __launch_bounds__(256) void theta_scan(
    const float* __restrict__ angP, const float* __restrict__ dtA,
    float* __restrict__ rc, float* __restrict__ rs) {
  const int h = blockIdx.x >> 5;
  const int r = blockIdx.x & 31;
  const int tid = threadIdx.x;
  __shared__ float ldssc[256];

  float csum[4];
  float run = 0.f;
#pragma unroll
  for (int i = 0; i < 4; ++i) {
    int l = tid * 4 + i;
    run += angP[l * NH + r] * dtA[l * NH + h];
    csum[i] = run;
  }
  ldssc[tid] = run;
  __syncthreads();
  for (int off = 1; off < 256; off <<= 1) {
    float t = (tid >= off) ? ldssc[tid - off] : 0.f;
    __syncthreads();
    ldssc[tid] += t;
    __syncthreads();
  }
  float excl = ldssc[tid] - run;
#pragma unroll
  for (int i = 0; i < 4; ++i) {
    int l = tid * 4 + i;
    float th = excl + csum[i];
    size_t o = ((size_t)l * NH + h) * RR + r;
    rc[o] = cosf(th);
    rs[o] = sinf(th);
  }
}

// ---------------------------------------------------------------------------
// uvgA: r13 structure; ph2/ph3 flattened to 640 independent (n, quarter)
// items over all 256 threads (was: 160 threads x 64/32 serial steps).
// Bit-identical outputs; 4x parallelism in the longest serial phases.
// ---------------------------------------------------------------------------
__global__ __launch_bounds__(256) void uvgA(
    const float* __restrict__ proj, const float* __restrict__ betaA,
    const float* __restrict__ gammaA, const float* __restrict__ lnaA,
    const float* __restrict__ rc, const float* __restrict__ rs,
    u16* __restrict__ U, float* __restrict__ cumA, float* __restrict__ adec,
    u16* __restrict__ S, u16* __restrict__ Yb) {
  const int h = blockIdx.x >> 4, c = blockIdx.x & 15;
  const int c0 = c * CL;
  const int tid = threadIdx.x;
  const int w = tid >> 6, lane = tid & 63;
  const int wr = w >> 1, wc = w & 1;
  const int fr = lane & 15, sl = lane >> 4;

  __shared__ __attribute__((aligned(16))) char smem[76288];
  u16 (*Gl)[72]   = (u16(*)[72])(smem);              // [64][72] raw G^T
  float* wsc      = (float*)(smem + 9216);           // [64]
  float* bet      = (float*)(smem + 9472);           // [64]
  float* gam      = (float*)(smem + 9728);           // [64]
  float* cums     = (float*)(smem + 9984);           // [64]
  float (*xs)[64] = (float(*)[64])(smem + 10240);    // [65][64]
  u16 (*Ul)[168]  = (u16(*)[168])(smem + 10240);     // aliases xs (after ph1)
  u16 (*Vl)[168]  = (u16(*)[168])(smem + 31744);     // [64][168]
  u16 (*Vt)[72]   = (u16(*)[72])(smem + 53248);      // [160][72] (scaled)
  u16 (*Ml)[72]   = (u16(*)[72])(smem + 53248);      // aliases Vt (after ph4)

  // ph0: stage xs; wave3: cumA scan + wsc/bet/gam/cums
  if (w < 3) {
    for (int i = tid; i < 65 * 16; i += 192) {
      int r = i >> 4, c4 = i & 15;
      int l = c0 - 1 + r;
      float4 v = {0.f, 0.f, 0.f, 0.f};
      if (l >= 0)
        v = *(const float4*)(proj + (size_t)l * NPROJ + OFF_X + h * HD + c4 * 4);
      *(float4*)&xs[r][c4 * 4] = v;
    }
  } else {
    const int t = lane;
    float v = lnaA[(c0 + t) * NH + h];
#pragma unroll
    for (int k = 1; k < 64; k <<= 1) {
      int src = t - k;
      float o = __shfl(v, src < 0 ? 0 : src);
      if (t >= k) v += o;
    }
    cumA[(size_t)h * L_SEQ + c0 + t] = v;
    if (t == 63) adec[h * NC + c] = expf(v);
    float c63 = __shfl(v, 63);
    cums[t] = v;
    wsc[t] = expf(c63 - v);
    bet[t] = betaA[(c0 + t) * NH + h];
    gam[t] = gammaA[(c0 + t) * NH + h];
  }
  __syncthreads();

  // ph1: G build (raw) -> Gl[p][s], lane = p
  {
    const int p = lane;
    union { u16 hh[16]; uint4 q[2]; } og;
    float xprev = xs[w * 16][p];
#pragma unroll
    for (int i = 0; i < 16; ++i) {
      int s = w * 16 + i;
      float xcur = xs[s + 1][p];
      og.hh[i] = f2bf(bet[s] * xprev + gam[s] * xcur);
      xprev = xcur;
    }
    *(uint4*)&Gl[p][w * 16] = og.q[0];
    *(uint4*)&Gl[p][w * 16 + 8] = og.q[1];
  }
  __syncthreads();       // xs dead; Ul region writable

  // ph2: U/V build — 640 items (n, quarter), n = it % 160 keeps lane
  // coalescing identical to the old layout; each item covers 16 ss steps.
  for (int it = tid; it < 640; it += 256) {
    const int n = it % 160;
    const int q = it / 160;
    const int idxB = (n < 64) ? (n & 31) : (n - 32);
    const bool is_re = (n < 32);
    const bool has_rot = (n < 64);
#pragma unroll
    for (int k = 0; k < 16; ++k) {
      int ss = q * 16 + k;
      int l = c0 + ss;
      const float* prow = proj + (size_t)l * NPROJ;
      float Bv = prow[OFF_B + idxB];
      float Cv = prow[OFF_C + idxB];
      if (has_rot) {
        float rv = is_re ? rc[((size_t)l * NH + h) * RR + idxB]
                         : rs[((size_t)l * NH + h) * RR + idxB];
        Bv *= rv; Cv *= rv;
      }
      u16 uu = f2bf(Cv);
      U[((size_t)h * L_SEQ + l) * NS + n] = uu;
      Ul[ss][n] = uu;
      Vl[ss][n] = f2bf(Bv);
    }
  }
  __syncthreads();

  // ph3: transpose+scale Vl -> Vt — 640 items (n, quarter of 8 s-pairs)
  for (int it = tid; it < 640; it += 256) {
    const int n = it % 160;
    const int q = it / 160;
#pragma unroll
    for (int k = 0; k < 8; ++k) {
      int s2 = q * 8 + k;
      float w0 = wsc[2 * s2], w1 = wsc[2 * s2 + 1];
      u32 lo = (u32)f2bf(bf2f(Vl[2 * s2][n]) * w0);
      u32 hi = (u32)f2bf(bf2f(Vl[2 * s2 + 1][n]) * w1);
      *(u32*)&Vt[n][2 * s2] = lo | (hi << 16);
    }
  }
  __syncthreads();

  // ph4: finals MFMA  F[p,n] = sum_s G[s,p] * wsc[s]*V[s,n]  (Gl x Vt)
  {
    f32x4 acc[2][5] = {};
#pragma unroll
    for (int ks = 0; ks < 2; ++ks) {
      bf16x8 a0 = *(const bf16x8*)&Gl[wr * 32 + fr][ks * 32 + sl * 8];
      bf16x8 a1 = *(const bf16x8*)&Gl[wr * 32 + 16 + fr][ks * 32 + sl * 8];
      bf16x8 bv[5];
#pragma unroll
      for (int fj = 0; fj < 5; ++fj)
        bv[fj] = *(const bf16x8*)&Vt[wc * 80 + fj * 16 + fr][ks * 32 + sl * 8];
#pragma unroll
      for (int fj = 0; fj < 5; ++fj) {
        acc[0][fj] = __builtin_amdgcn_mfma_f32_16x16x32_bf16(a0, bv[fj], acc[0][fj], 0, 0, 0);
        acc[1][fj] = __builtin_amdgcn_mfma_f32_16x16x32_bf16(a1, bv[fj], acc[1][fj], 0, 0, 0);
      }
    }
    u16* Fb = S + (size_t)(c * NH + h) * HD * NS;
#pragma unroll
    for (int fi = 0; fi < 2; ++fi)
#pragma unroll
      for (int fj = 0; fj < 5; ++fj)
#pragma unroll
        for (int r = 0; r < 4; ++r) {
          int p = wr * 32 + fi * 16 + sl * 4 + r;
          int n = wc * 80 + fj * 16 + fr;
          Fb[(size_t)p * NS + n] = f2bf(acc[fi][fj][r]);
        }
  }

  // ph5: P1 = Ul @ Vl^T (t rows, s cols), then M -> Ml (overwrites Vt)
  f32x4 pac[2][2] = {};
#pragma unroll
  for (int ks = 0; ks < 5; ++ks) {
    bf16x8 a0 = *(const bf16x8*)&Ul[wr * 32 + fr][ks * 32 + sl * 8];
    bf16x8 a1 = *(const bf16x8*)&Ul[wr * 32 + 16 + fr][ks * 32 + sl * 8];
    bf16x8 b0 = *(const bf16x8*)&Vl[wc * 32 + fr][ks * 32 + sl * 8];
    bf16x8 b1 = *(const bf16x8*)&Vl[wc * 32 + 16 + fr][ks * 32 + sl * 8];
    pac[0][0] = __builtin_amdgcn_mfma_f32_16x16x32_bf16(a0, b0, pac[0][0], 0, 0, 0);
    pac[0][1] = __builtin_amdgcn_mfma_f32_16x16x32_bf16(a0, b1, pac[0][1], 0, 0, 0);
    pac[1][0] = __builtin_amdgcn_mfma_f32_16x16x32_bf16(a1, b0, pac[1][0], 0, 0, 0);
    pac[1][1] = __builtin_amdgcn_mfma_f32_16x16x32_bf16(a1, b1, pac[1][1], 0, 0, 0);
  }
  __syncthreads();   // all waves done reading Vt (ph4) before Ml overwrite
#pragma unroll
  for (int fi = 0; fi < 2; ++fi)
#pragma unroll
    for (int fj = 0; fj < 2; ++fj)
#pragma unroll
      for (int r = 0; r < 4; ++r) {
        int t = wr * 32 + fi * 16 + sl * 4 + r;
        int ss = wc * 32 + fj * 16 + fr;
        float m = (ss <= t) ? expf(cums[t] - cums[ss]) * pac[fi][fj][r] : 0.f;
        Ml[t][ss] = f2bf(m);
      }
  __syncthreads();

  // ph6: Yintra = Ml @ Gl^T  -> Yb (bf16)
  {
    f32x4 yac[2][2] = {};
#pragma unroll
    for (int ks = 0; ks < 2; ++ks) {
      bf16x8 a0 = *(const bf16x8*)&Ml[wr * 32 + fr][ks * 32 + sl * 8];
      bf16x8 a1 = *(const bf16x8*)&Ml[wr * 32 + 16 + fr][ks * 32 + sl * 8];
      bf16x8 b0 = *(const bf16x8*)&Gl[wc * 32 + fr][ks * 32 + sl * 8];
      bf16x8 b1 = *(const bf16x8*)&Gl[wc * 32 + 16 + fr][ks * 32 + sl * 8];
      yac[0][0] = __builtin_amdgcn_mfma_f32_16x16x32_bf16(a0, b0, yac[0][0], 0, 0, 0);
      yac[0][1] = __builtin_amdgcn_mfma_f32_16x16x32_bf16(a0, b1, yac[0][1], 0, 0, 0);
      yac[1][0] = __builtin_amdgcn_mfma_f32_16x16x32_bf16(a1, b0, yac[1][0], 0, 0, 0);
      yac[1][1] = __builtin_amdgcn_mfma_f32_16x16x32_bf16(a1, b1, yac[1][1], 0, 0, 0);
    }
#pragma unroll
    for (int fi = 0; fi < 2; ++fi)
#pragma unroll
      for (int fj = 0; fj < 2; ++fj)
#pragma unroll
        for (int r = 0; r < 4; ++r) {
          int t = wr * 32 + fi * 16 + sl * 4 + r;
          int p = wc * 32 + fj * 16 + fr;
          Yb[(size_t)(c0 + t) * DINNER + h * HD + p] = f2bf(yac[fi][fj][r]);
        }
  }
}

// ---------------------------------------------------------------------------
// combine (r11-exact): sequential over 16 chunks per (h,p,n); finals->inits.
// ---------------------------------------------------------------------------
__global__ __launch_bounds__(256) void combine(
    u16* __restrict__ S, const float* __restrict__ adec) {
  const int idx = blockIdx.x * 256 + threadIdx.x;
  if (idx >= NH * HD * NS) return;
  const int n = idx % NS;
  const int rem = idx / NS;
  const int p = rem & 63;
  const int h = rem >> 6;
  float F = 0.f;
  for (int c = 0; c < NC; ++c) {
    size_t off = ((size_t)(c * NH + h) * HD + p) * NS + n;
    float sv = bf2f(S[off]);
    S[off] = f2bf(F);
    F = fmaf(F, adec[h * NC + c], sv);
  }
}

// ---------------------------------------------------------------------------
// passC (r13-exact): y = ecum[t]*(U@S0^T) + Yintra + D*x, gated. One barrier.
// ---------------------------------------------------------------------------
__global__ __launch_bounds__(256) void passC(
    const float* __restrict__ proj, const u16* __restrict__ U,
    const float* __restrict__ cumA, const u16* __restrict__ S,
    const u16* __restrict__ Yb, const float* __restrict__ Dvec,
    u16* __restrict__ yz) {
  const int c = blockIdx.x >> 5, h = blockIdx.x & 31;
  const int c0 = c * CL;
  const int tid = threadIdx.x;
  const int w = tid >> 6, lane = tid & 63;
  const int wr = w >> 1, wc = w & 1;
  const int fr = lane & 15, sl = lane >> 4;
  __shared__ u16 Ul[64][168];
  __shared__ u16 BB[64][168];
  __shared__ float ecum[64];

  const u16* Us = U + ((size_t)h * L_SEQ + c0) * NS;
  for (int i = tid; i < 1280; i += 256) {
    int r = i / 20, ch = i % 20;
    *(uint4*)&Ul[r][ch * 8] = *(const uint4*)(Us + (size_t)r * NS + ch * 8);
  }
  {
    const u16* S0 = S + (size_t)(c * NH + h) * HD * NS;
    for (int i = tid; i < 1280; i += 256) {
      int r = i / 20, ch = i % 20;
      *(uint4*)&BB[r][ch * 8] = *(const uint4*)(S0 + (size_t)r * NS + ch * 8);
    }
  }
  if (tid < 64) ecum[tid] = expf(cumA[(size_t)h * L_SEQ + c0 + tid]);
  __syncthreads();

  f32x4 acc[2][2] = {};
#pragma unroll
  for (int ks = 0; ks < 5; ++ks) {
    bf16x8 a0 = *(const bf16x8*)&Ul[wr * 32 + fr][ks * 32 + sl * 8];
    bf16x8 a1 = *(const bf16x8*)&Ul[wr * 32 + 16 + fr][ks * 32 + sl * 8];
    bf16x8 b0 = *(const bf16x8*)&BB[wc * 32 + fr][ks * 32 + sl * 8];
    bf16x8 b1 = *(const bf16x8*)&BB[wc * 32 + 16 + fr][ks * 32 + sl * 8];
    acc[0][0] = __builtin_amdgcn_mfma_f32_16x16x32_bf16(a0, b0, acc[0][0], 0, 0, 0);
    acc[0][1] = __builtin_amdgcn_mfma_f32_16x16x32_bf16(a0, b1, acc[0][1], 0, 0, 0);
    acc[1][0] = __builtin_amdgcn_mfma_f32_16x16x32_bf16(a1, b0, acc[1][0], 0, 0, 0);
    acc[1][1] = __builtin_amdgcn_mfma_f32_16x16x32_bf16(a1, b1, acc[1][1], 0, 0, 0);
  }

  const float Dh = Dvec[h];
#pragma unroll
  for (int fi = 0; fi < 2; ++fi)
#pragma unroll
    for (int fj = 0; fj < 2; ++fj)
#pragma unroll
      for (int r = 0; r < 4; ++r) {
        int t = wr * 32 + fi * 16 + sl * 4 + r;
        int p = wc * 32 + fj * 16 + fr;
        int l = c0 + t;
        float y = acc[fi][fj][r] * ecum[t] +
                  bf2f(Yb[(size_t)l * DINNER + h * HD + p]);
        float x = proj[(size_t)l * NPROJ + OFF_X + h * HD + p];
        float z = proj[(size_t)l * NPROJ + OFF_Z + h * HD + p];
        y += Dh * x;
        float sg = z / (1.f + expf(-z));
        yz[(size_t)l * DINNER + h * HD + p] = f2bf(y * sg);
      }
}

// ---------------------------------------------------------------------------
extern "C" void kernel_launch(void* const* d_in, const int* in_sizes, int n_in,
                              void* d_out, int out_size, void* d_ws, size_t ws_size,
                              hipStream_t stream) {
  const float* u       = (const float*)d_in[0];
  const float* w_in    = (const float*)d_in[1];
  const float* w_out   = (const float*)d_in[2];
  const float* dt_bias = (const float*)d_in[3];
  const float* Dvec    = (const float*)d_in[4];
  float* out = (float*)d_out;

  float* ws = (float*)d_ws;
  float* proj   = ws;                          // 4,587,520 f
  float* dtA    = proj + 4587520;              // 32768
  float* lnaA   = dtA + 32768;
  float* betaA  = lnaA + 32768;
  float* gammaA = betaA + 32768;
  float* cumA   = gammaA + 32768;
  float* adec   = cumA + 32768;                // 512
  float* angP   = adec + 512;                  // 32768
  float* rcb    = angP + 32768;                // 1,048,576
  float* rsb    = rcb + 1048576;               // 1,048,576
  u16*   Sb     = (u16*)(rsb + 1048576);       // 5,242,880 u16 (chunk states)
  u16*   Ubuf   = Sb + 5242880;                // 5,242,880 u16
  u16*   Yb     = Ubuf + 5242880;              // 2,097,152 u16 (Yintra)
  u16*   yzb    = Yb + 2097152;                // 2,097,152 u16
  u16*   wob    = yzb + 2097152;               // 2,097,152 u16
  // epoch-1 overlay (dead before uvgA writes Sb/Ubuf):
  u16*   ub     = Sb;                          // 1,048,576 u16
  u16*   wib    = Sb + 1048576;                // 4,587,520 u16 (spills into Ubuf)

  // 1. u + w_in -> bf16
  cvt2_bf16<<<(131072 + 573440) / 256, 256, 0, stream>>>(
      u, ub, 131072, w_in, wib, 573440);

  // 2. proj = u @ w_in^T  (64x128, 560 blocks, XCD-swizzled)
  gemm_bf16<64, 128, 16, 560><<<560, 256, 0, stream>>>(
      ub, wib, proj, NPROJ, DMODEL);

  // 3. w_out cvt + scalars
  prep_scalars_cvt<<<1024 + 128, 256, 0, stream>>>(
      proj, dt_bias, dtA, lnaA, betaA, gammaA, angP, w_out, wob);

  // 4. theta -> rc, rs
  theta_scan<<<NH * RR, 256, 0, stream>>>(angP, dtA, rcb, rsb);

  // 5. U/cumA build + chunk finals + intra-chunk Y (V/Gt stay in LDS)
  uvgA<<<NH * NC, 256, 0, stream>>>(
      proj, betaA, gammaA, lnaA, rcb, rsb, Ubuf, cumA, adec, Sb, Yb);

  // 6. cross-chunk combine
  combine<<<(NH * HD * NS + 255) / 256, 256, 0, stream>>>(Sb, adec);

  // 7. y = P2*ecum + Yintra + D*x, gate -> yz
  passC<<<NC * NH, 256, 0, stream>>>(
      proj, Ubuf, cumA, Sb, Yb, Dvec, yzb);

  // 8. out = yz @ w_out^T  (64x64, 256 blocks, XCD-swizzled)
  gemm_bf16<64, 64, 16, 256><<<256, 256, 0, stream>>>(
      yzb, wob, out, DMODEL, DINNER);
}